// Round 6
// baseline (413.566 us; speedup 1.0000x reference)
//
#include <hip/hip_runtime.h>

#define N_NODES 100000
#define D_IN 32
#define H 64
#define EPS 1e-5f
#define CAP 32      // bucket capacity; P(Poisson(12.5) > 32) ~ 1e-6/node
#define CSTR 16     // counter stride (ints): one counter per 64B line
#define OV_CAP 32768

__device__ __forceinline__ unsigned short f2bf(float f) {
    union { float f; unsigned int u; } c; c.f = f;
    unsigned int b = c.u + 0x7FFFu + ((c.u >> 16) & 1u);   // RNE
    return (unsigned short)(b >> 16);
}
__device__ __forceinline__ float bf2f(unsigned short s) {
    union { unsigned int u; float f; } c; c.u = ((unsigned int)s) << 16;
    return c.f;
}

// ================= fused mlp + scatter =================
// blocks [0, SB): edge scatter (latency/atomic-bound)
// blocks [SB, SB+MB): node MLP, 2 threads per node (VALU-bound)
// Independent work on different pipes -> concurrent execution, time ~ max.
// MLP split across thread pairs keeps VGPR ~<=128 so scatter occupancy stays high.
__global__ __launch_bounds__(256, 2) void fused_kernel(
    const float* __restrict__ x,
    const float* __restrict__ W1, const float* __restrict__ b1,
    const float* __restrict__ g1, const float* __restrict__ be1,
    const float* __restrict__ W2, const float* __restrict__ b2,
    const float* __restrict__ g2, const float* __restrict__ be2,
    unsigned short* __restrict__ hb,
    const int* __restrict__ ei,
    int* __restrict__ cnt, int* __restrict__ bkt,
    int* __restrict__ ovCnt, int2* __restrict__ ov,
    int E, int SB)
{
    if (blockIdx.x < (unsigned)SB) {
        // ---------------- scatter: 8 edges/thread ----------------
        int t = blockIdx.x * 256 + threadIdx.x;
        int e0 = t * 8;
        if (e0 >= E) return;

        int rows[8], cols[8], pos[8];
        if (e0 + 7 < E) {
            int4 r0 = *(const int4*)(ei + e0);
            int4 r1 = *(const int4*)(ei + e0 + 4);
            int4 c0 = *(const int4*)(ei + E + e0);
            int4 c1 = *(const int4*)(ei + E + e0 + 4);
            rows[0]=r0.x; rows[1]=r0.y; rows[2]=r0.z; rows[3]=r0.w;
            rows[4]=r1.x; rows[5]=r1.y; rows[6]=r1.z; rows[7]=r1.w;
            cols[0]=c0.x; cols[1]=c0.y; cols[2]=c0.z; cols[3]=c0.w;
            cols[4]=c1.x; cols[5]=c1.y; cols[6]=c1.z; cols[7]=c1.w;
        } else {
#pragma unroll
            for (int j = 0; j < 8; ++j) {
                int e = e0 + j;
                if (e < E) { rows[j] = ei[e]; cols[j] = ei[E + e]; }
                else rows[j] = -1;
            }
        }
#pragma unroll
        for (int j = 0; j < 8; ++j)
            if (rows[j] >= 0) pos[j] = atomicAdd(&cnt[rows[j] * CSTR], 1);
#pragma unroll
        for (int j = 0; j < 8; ++j) {
            if (rows[j] < 0) continue;
            if (pos[j] < CAP) {
                bkt[rows[j] * CAP + pos[j]] = cols[j];
            } else {
                int s = atomicAdd(ovCnt, 1);
                if (s < OV_CAP) ov[s] = make_int2(rows[j], cols[j]);
            }
        }
        return;
    }

    // ---------------- MLP: 2 threads per node, 32 channels each ----------------
    int t = (blockIdx.x - SB) * 256 + threadIdx.x;
    int node = t >> 1;
    if (node >= N_NODES) node = N_NODES - 1;   // uniform CF; dup same-value stores
    const int half = t & 1;
    const int coff = half * 32;                // this thread's channel offset

    float xr[D_IN];
    {
        const float4* xp = (const float4*)(x + (long long)node * D_IN);
#pragma unroll
        for (int i = 0; i < D_IN / 4; ++i) {
            float4 v = xp[i];
            xr[4*i+0] = v.x; xr[4*i+1] = v.y; xr[4*i+2] = v.z; xr[4*i+3] = v.w;
        }
    }

    float h1[32];
#pragma unroll
    for (int jb = 0; jb < 8; ++jb) {
        float4 b = *(const float4*)(b1 + coff + jb * 4);
        h1[4*jb+0] = b.x; h1[4*jb+1] = b.y; h1[4*jb+2] = b.z; h1[4*jb+3] = b.w;
    }
#pragma unroll
    for (int k = 0; k < D_IN; ++k) {
        float xk = xr[k];
#pragma unroll
        for (int jb = 0; jb < 8; ++jb) {
            float4 w = *(const float4*)(W1 + k * H + coff + jb * 4);
            h1[4*jb+0] += xk * w.x; h1[4*jb+1] += xk * w.y;
            h1[4*jb+2] += xk * w.z; h1[4*jb+3] += xk * w.w;
        }
    }
    // LN1 (+pair reduce) + ReLU
    {
        float s = 0.f, q = 0.f;
#pragma unroll
        for (int j = 0; j < 32; ++j) { s += h1[j]; q += h1[j] * h1[j]; }
        s += __shfl_xor(s, 1);
        q += __shfl_xor(q, 1);
        float mu  = s * (1.0f / H);
        float var = q * (1.0f / H) - mu * mu;
        float rs  = rsqrtf(var + EPS);
#pragma unroll
        for (int jb = 0; jb < 8; ++jb) {
            float4 g  = *(const float4*)(g1 + coff + jb * 4);
            float4 be = *(const float4*)(be1 + coff + jb * 4);
            h1[4*jb+0] = fmaxf((h1[4*jb+0]-mu)*rs*g.x + be.x, 0.0f);
            h1[4*jb+1] = fmaxf((h1[4*jb+1]-mu)*rs*g.y + be.y, 0.0f);
            h1[4*jb+2] = fmaxf((h1[4*jb+2]-mu)*rs*g.z + be.z, 0.0f);
            h1[4*jb+3] = fmaxf((h1[4*jb+3]-mu)*rs*g.w + be.w, 0.0f);
        }
    }

    float h2[32];
#pragma unroll
    for (int jb = 0; jb < 8; ++jb) {
        float4 b = *(const float4*)(b2 + coff + jb * 4);
        h2[4*jb+0] = b.x; h2[4*jb+1] = b.y; h2[4*jb+2] = b.z; h2[4*jb+3] = b.w;
    }
    // layer 2: k in [0,64); value for k=j lives in half0's h1[j], k=32+j in half1's
#pragma unroll
    for (int j = 0; j < 32; ++j) {
        float oth = __shfl_xor(h1[j], 1);
        float klo = half ? oth : h1[j];
        float khi = half ? h1[j] : oth;
#pragma unroll
        for (int jb = 0; jb < 8; ++jb) {
            float4 wl = *(const float4*)(W2 + j * H + coff + jb * 4);
            float4 wh = *(const float4*)(W2 + (32 + j) * H + coff + jb * 4);
            h2[4*jb+0] += klo * wl.x + khi * wh.x;
            h2[4*jb+1] += klo * wl.y + khi * wh.y;
            h2[4*jb+2] += klo * wl.z + khi * wh.z;
            h2[4*jb+3] += klo * wl.w + khi * wh.w;
        }
    }
    // LN2 (+pair reduce) + ReLU + bf16 store
    {
        float s = 0.f, q = 0.f;
#pragma unroll
        for (int j = 0; j < 32; ++j) { s += h2[j]; q += h2[j] * h2[j]; }
        s += __shfl_xor(s, 1);
        q += __shfl_xor(q, 1);
        float mu  = s * (1.0f / H);
        float var = q * (1.0f / H) - mu * mu;
        float rs  = rsqrtf(var + EPS);

        unsigned short* hp = hb + (long long)node * H + coff;
#pragma unroll
        for (int jb = 0; jb < 8; ++jb) {
            float4 g  = *(const float4*)(g2 + coff + jb * 4);
            float4 be = *(const float4*)(be2 + coff + jb * 4);
            ushort4 u;
            u.x = f2bf(fmaxf((h2[4*jb+0]-mu)*rs*g.x + be.x, 0.0f));
            u.y = f2bf(fmaxf((h2[4*jb+1]-mu)*rs*g.y + be.y, 0.0f));
            u.z = f2bf(fmaxf((h2[4*jb+2]-mu)*rs*g.z + be.z, 0.0f));
            u.w = f2bf(fmaxf((h2[4*jb+3]-mu)*rs*g.w + be.w, 0.0f));
            *(ushort4*)(hp + 4*jb) = u;
        }
    }
}

// ================= pull aggregation =================
// Wave per node. Lane = (half, c2): c2 indexes a ushort2 (2 channels, 4B),
// half selects edge-of-pair -> each gather instr fetches 2 full rows (256B),
// 16 edges in flight per iteration. Halves combined via shfl_xor(32).
__global__ __launch_bounds__(256) void aggr_kernel(
    const int* __restrict__ cnt, const int* __restrict__ bkt,
    const unsigned short* __restrict__ hb, float* __restrict__ out,
    const int* __restrict__ ovCnt, const int2* __restrict__ ov)
{
    int lane = threadIdx.x & 63;
    int node = blockIdx.x * 4 + (threadIdx.x >> 6);
    if (node >= N_NODES) return;
    const int half = lane >> 5;
    const int c2   = lane & 31;

    int m = cnt[node * CSTR];
    if (m > CAP) m = CAP;
    const int* b = bkt + node * CAP;
    const unsigned int* hb2 = (const unsigned int*)hb;   // row stride 32 uints

    float accx = 0.f, accy = 0.f;
    for (int i0 = 0; i0 < m; i0 += 16) {
        int4 q0 = *(const int4*)(b + i0);
        int4 q1 = *(const int4*)(b + i0 + 4);
        int4 q2 = *(const int4*)(b + i0 + 8);
        int4 q3 = *(const int4*)(b + i0 + 12);
        int qq[16] = {q0.x,q0.y,q0.z,q0.w, q1.x,q1.y,q1.z,q1.w,
                      q2.x,q2.y,q2.z,q2.w, q3.x,q3.y,q3.z,q3.w};
        int mm = m - i0;
        unsigned int v[8];
#pragma unroll
        for (int j = 0; j < 8; ++j) {           // 8 gathers in flight, 2 edges each
            int e = 2*j + half;
            int col = half ? qq[2*j+1] : qq[2*j];
            if (e < mm) v[j] = hb2[col * 32 + c2];
        }
#pragma unroll
        for (int j = 0; j < 8; ++j) {
            int e = 2*j + half;
            if (e < mm) {
                accx += bf2f((unsigned short)(v[j] & 0xFFFFu));
                accy += bf2f((unsigned short)(v[j] >> 16));
            }
        }
    }
    // combine the two half-wave edge subsets
    accx += __shfl_xor(accx, 32);
    accy += __shfl_xor(accy, 32);

    // exact overflow drain (normally 0) + self term + store: half 0 only
    int nov = *ovCnt; if (nov > OV_CAP) nov = OV_CAP;
    if (half == 0) {
        for (int i = 0; i < nov; ++i) {
            int2 rc = ov[i];
            if (rc.x == node) {
                unsigned int vv = hb2[rc.y * 32 + c2];
                accx += bf2f((unsigned short)(vv & 0xFFFFu));
                accy += bf2f((unsigned short)(vv >> 16));
            }
        }
        unsigned int sv = hb2[node * 32 + c2];
        accx += bf2f((unsigned short)(sv & 0xFFFFu));
        accy += bf2f((unsigned short)(sv >> 16));
        *(float2*)(out + (long long)node * H + 2 * c2) = make_float2(accx, accy);
    }
}

extern "C" void kernel_launch(void* const* d_in, const int* in_sizes, int n_in,
                              void* d_out, int out_size, void* d_ws, size_t ws_size,
                              hipStream_t stream)
{
    const float* x   = (const float*)d_in[0];
    const int*   ei  = (const int*)d_in[1];
    const float* W1  = (const float*)d_in[2];
    const float* b1  = (const float*)d_in[3];
    const float* g1  = (const float*)d_in[4];
    const float* be1 = (const float*)d_in[5];
    const float* W2  = (const float*)d_in[6];
    const float* b2  = (const float*)d_in[7];
    const float* g2  = (const float*)d_in[8];
    const float* be2 = (const float*)d_in[9];

    float* out = (float*)d_out;

    // workspace layout (~32.3 MB)
    char* ws = (char*)d_ws;
    unsigned short* hb    = (unsigned short*)ws;        // 12,800,000 B
    int*            cnt   = (int*)(ws + 12800000);      //  6,400,000 B
    int*            ovCnt = (int*)(ws + 19200000);      //         64 B
    int2*           ov    = (int2*)(ws + 19200064);     //    262,144 B
    int*            bkt   = (int*)(ws + 19462208);      // 12,800,000 B

    const int E = in_sizes[1] / 2;

    hipMemsetAsync(cnt, 0, 6400064, stream);            // cnt + ovCnt

    const int SB = ((E + 7) / 8 + 255) / 256;           // scatter blocks (611)
    const int MB = (2 * N_NODES + 255) / 256;           // mlp blocks (782)
    fused_kernel<<<SB + MB, 256, 0, stream>>>(
        x, W1, b1, g1, be1, W2, b2, g2, be2, hb,
        ei, cnt, bkt, ovCnt, ov, E, SB);

    aggr_kernel<<<(N_NODES + 3) / 4, 256, 0, stream>>>(cnt, bkt, hb, out, ovCnt, ov);
}

// Round 7
// 292.203 us; speedup vs baseline: 1.4153x; 1.4153x over previous
//
#include <hip/hip_runtime.h>

#define N_NODES 100000
#define D_IN 32
#define H 64
#define EPS 1e-5f
#define CAP 32      // bucket capacity; P(Poisson(12.5) > 32) ~ 1e-6/node
#define CSTR 16     // counter stride (ints): one counter per 64B line
#define OV_CAP 32768

__device__ __forceinline__ unsigned short f2bf(float f) {
    union { float f; unsigned int u; } c; c.f = f;
    unsigned int b = c.u + 0x7FFFu + ((c.u >> 16) & 1u);   // RNE
    return (unsigned short)(b >> 16);
}
__device__ __forceinline__ float bf2f(unsigned short s) {
    union { unsigned int u; float f; } c; c.u = ((unsigned int)s) << 16;
    return c.f;
}

// ---------------- node MLP: thread-per-node (R5, known-good) ----------------
// Uniform CF -> weight loads scalarize; __launch_bounds__(256,2) gives the
// 256-VGPR budget that keeps h1[64]+h2[64] in registers (R4 spilled at 72).
__global__ __launch_bounds__(256, 2) void mlp_kernel(
    const float* __restrict__ x,
    const float* __restrict__ W1, const float* __restrict__ b1,
    const float* __restrict__ g1, const float* __restrict__ be1,
    const float* __restrict__ W2, const float* __restrict__ b2,
    const float* __restrict__ g2, const float* __restrict__ be2,
    unsigned short* __restrict__ hb)
{
    int gid = blockIdx.x * blockDim.x + threadIdx.x;
    int node = gid < N_NODES ? gid : N_NODES - 1;

    float xr[D_IN];
    {
        const float4* xp = (const float4*)(x + (long long)node * D_IN);
#pragma unroll
        for (int i = 0; i < D_IN / 4; ++i) {
            float4 v = xp[i];
            xr[4*i+0] = v.x; xr[4*i+1] = v.y; xr[4*i+2] = v.z; xr[4*i+3] = v.w;
        }
    }

    float h1[H];
#pragma unroll
    for (int jb = 0; jb < H / 4; ++jb) {
        float4 b = *(const float4*)(b1 + jb * 4);
        h1[4*jb+0] = b.x; h1[4*jb+1] = b.y; h1[4*jb+2] = b.z; h1[4*jb+3] = b.w;
    }
#pragma unroll
    for (int k = 0; k < D_IN; ++k) {
        float xk = xr[k];
#pragma unroll
        for (int jb = 0; jb < H / 4; ++jb) {
            float4 w = *(const float4*)(W1 + k * H + jb * 4);
            h1[4*jb+0] += xk * w.x; h1[4*jb+1] += xk * w.y;
            h1[4*jb+2] += xk * w.z; h1[4*jb+3] += xk * w.w;
        }
    }
    {
        float s0=0,s1=0,s2=0,s3=0, q0=0,q1=0,q2=0,q3=0;
#pragma unroll
        for (int j = 0; j < H; j += 4) {
            s0 += h1[j+0]; s1 += h1[j+1]; s2 += h1[j+2]; s3 += h1[j+3];
            q0 += h1[j+0]*h1[j+0]; q1 += h1[j+1]*h1[j+1];
            q2 += h1[j+2]*h1[j+2]; q3 += h1[j+3]*h1[j+3];
        }
        float mu  = (s0+s1+s2+s3) * (1.0f / H);
        float var = (q0+q1+q2+q3) * (1.0f / H) - mu * mu;
        float rs  = rsqrtf(var + EPS);
#pragma unroll
        for (int jb = 0; jb < H / 4; ++jb) {
            float4 g = *(const float4*)(g1 + jb * 4);
            float4 be = *(const float4*)(be1 + jb * 4);
            h1[4*jb+0] = fmaxf((h1[4*jb+0]-mu)*rs*g.x + be.x, 0.0f);
            h1[4*jb+1] = fmaxf((h1[4*jb+1]-mu)*rs*g.y + be.y, 0.0f);
            h1[4*jb+2] = fmaxf((h1[4*jb+2]-mu)*rs*g.z + be.z, 0.0f);
            h1[4*jb+3] = fmaxf((h1[4*jb+3]-mu)*rs*g.w + be.w, 0.0f);
        }
    }

    float h2[H];
#pragma unroll
    for (int jb = 0; jb < H / 4; ++jb) {
        float4 b = *(const float4*)(b2 + jb * 4);
        h2[4*jb+0] = b.x; h2[4*jb+1] = b.y; h2[4*jb+2] = b.z; h2[4*jb+3] = b.w;
    }
#pragma unroll
    for (int k = 0; k < H; ++k) {
        float hk = h1[k];
#pragma unroll
        for (int jb = 0; jb < H / 4; ++jb) {
            float4 w = *(const float4*)(W2 + k * H + jb * 4);
            h2[4*jb+0] += hk * w.x; h2[4*jb+1] += hk * w.y;
            h2[4*jb+2] += hk * w.z; h2[4*jb+3] += hk * w.w;
        }
    }
    {
        float s0=0,s1=0,s2=0,s3=0, q0=0,q1=0,q2=0,q3=0;
#pragma unroll
        for (int j = 0; j < H; j += 4) {
            s0 += h2[j+0]; s1 += h2[j+1]; s2 += h2[j+2]; s3 += h2[j+3];
            q0 += h2[j+0]*h2[j+0]; q1 += h2[j+1]*h2[j+1];
            q2 += h2[j+2]*h2[j+2]; q3 += h2[j+3]*h2[j+3];
        }
        float mu  = (s0+s1+s2+s3) * (1.0f / H);
        float var = (q0+q1+q2+q3) * (1.0f / H) - mu * mu;
        float rs  = rsqrtf(var + EPS);

        unsigned short* hp = hb + (long long)node * H;
#pragma unroll
        for (int jb = 0; jb < H / 4; ++jb) {
            float4 g = *(const float4*)(g2 + jb * 4);
            float4 be = *(const float4*)(be2 + jb * 4);
            ushort4 u;
            u.x = f2bf(fmaxf((h2[4*jb+0]-mu)*rs*g.x + be.x, 0.0f));
            u.y = f2bf(fmaxf((h2[4*jb+1]-mu)*rs*g.y + be.y, 0.0f));
            u.z = f2bf(fmaxf((h2[4*jb+2]-mu)*rs*g.z + be.z, 0.0f));
            u.w = f2bf(fmaxf((h2[4*jb+3]-mu)*rs*g.w + be.w, 0.0f));
            *(ushort4*)(hp + 4*jb) = u;
        }
    }
}

// ---------------- edge scatter: 8 edges/thread (R5, known-good) ----------------
__global__ __launch_bounds__(256) void scatter_kernel(
    const int* __restrict__ ei,
    int* __restrict__ cnt, int* __restrict__ bkt,
    int* __restrict__ ovCnt, int2* __restrict__ ov, int E)
{
    int t = blockIdx.x * blockDim.x + threadIdx.x;
    int e0 = t * 8;
    if (e0 >= E) return;

    int rows[8], cols[8], pos[8];
    if (e0 + 7 < E) {
        int4 r0 = *(const int4*)(ei + e0);
        int4 r1 = *(const int4*)(ei + e0 + 4);
        int4 c0 = *(const int4*)(ei + E + e0);
        int4 c1 = *(const int4*)(ei + E + e0 + 4);
        rows[0]=r0.x; rows[1]=r0.y; rows[2]=r0.z; rows[3]=r0.w;
        rows[4]=r1.x; rows[5]=r1.y; rows[6]=r1.z; rows[7]=r1.w;
        cols[0]=c0.x; cols[1]=c0.y; cols[2]=c0.z; cols[3]=c0.w;
        cols[4]=c1.x; cols[5]=c1.y; cols[6]=c1.z; cols[7]=c1.w;
    } else {
#pragma unroll
        for (int j = 0; j < 8; ++j) {
            int e = e0 + j;
            if (e < E) { rows[j] = ei[e]; cols[j] = ei[E + e]; }
            else rows[j] = -1;
        }
    }
#pragma unroll
    for (int j = 0; j < 8; ++j)
        if (rows[j] >= 0) pos[j] = atomicAdd(&cnt[rows[j] * CSTR], 1);
#pragma unroll
    for (int j = 0; j < 8; ++j) {
        if (rows[j] < 0) continue;
        if (pos[j] < CAP) {
            bkt[rows[j] * CAP + pos[j]] = cols[j];
        } else {
            int s = atomicAdd(ovCnt, 1);
            if (s < OV_CAP) ov[s] = make_int2(rows[j], cols[j]);
        }
    }
}

// ---------------- pull aggregation: whole bucket + all gathers in flight ----------------
// node (hence m) is wave-uniform: load all ceil(m/4) int4 bucket chunks first
// (independent), then issue every gather + the self-term before accumulating.
// Serial memory rounds per node: cnt -> bucket -> gathers (3, was ~4-5).
__global__ __launch_bounds__(256) void aggr_kernel(
    const int* __restrict__ cnt, const int* __restrict__ bkt,
    const unsigned short* __restrict__ hb, float* __restrict__ out,
    const int* __restrict__ ovCnt, const int2* __restrict__ ov)
{
    int lane = threadIdx.x & 63;
    int node = blockIdx.x * (blockDim.x >> 6) + (threadIdx.x >> 6);
    if (node >= N_NODES) return;

    int m = cnt[node * CSTR];
    if (m > CAP) m = CAP;
    const int4* b4 = (const int4*)(bkt + node * CAP);

    // load entire bucket (int4 chunks; trailing garbage never used as address)
    int cols[CAP];
#pragma unroll
    for (int i = 0; i < CAP / 4; ++i) {
        if (i * 4 < m) {
            int4 q = b4[i];
            cols[4*i+0] = q.x; cols[4*i+1] = q.y;
            cols[4*i+2] = q.z; cols[4*i+3] = q.w;
        }
    }

    // all gathers independent & in flight (plus self-term)
    unsigned short v[CAP];
#pragma unroll
    for (int j = 0; j < CAP; ++j)
        if (j < m) v[j] = hb[cols[j] * H + lane];
    float self = bf2f(hb[node * H + lane]);

    float a0 = 0.f, a1 = 0.f, a2 = 0.f, a3 = 0.f;
#pragma unroll
    for (int j = 0; j < CAP; j += 4) {
        if (j + 0 < m) a0 += bf2f(v[j+0]);
        if (j + 1 < m) a1 += bf2f(v[j+1]);
        if (j + 2 < m) a2 += bf2f(v[j+2]);
        if (j + 3 < m) a3 += bf2f(v[j+3]);
    }
    float acc = (a0 + a1) + (a2 + a3);

    // exact overflow drain (normally 0)
    int nov = *ovCnt; if (nov > OV_CAP) nov = OV_CAP;
    for (int i = 0; i < nov; ++i) {
        int2 rc = ov[i];
        if (rc.x == node) acc += bf2f(hb[rc.y * H + lane]);
    }

    out[node * H + lane] = self + acc;
}

extern "C" void kernel_launch(void* const* d_in, const int* in_sizes, int n_in,
                              void* d_out, int out_size, void* d_ws, size_t ws_size,
                              hipStream_t stream)
{
    const float* x   = (const float*)d_in[0];
    const int*   ei  = (const int*)d_in[1];
    const float* W1  = (const float*)d_in[2];
    const float* b1  = (const float*)d_in[3];
    const float* g1  = (const float*)d_in[4];
    const float* be1 = (const float*)d_in[5];
    const float* W2  = (const float*)d_in[6];
    const float* b2  = (const float*)d_in[7];
    const float* g2  = (const float*)d_in[8];
    const float* be2 = (const float*)d_in[9];

    float* out = (float*)d_out;

    // workspace layout (~32.3 MB)
    char* ws = (char*)d_ws;
    unsigned short* hb    = (unsigned short*)ws;        // 12,800,000 B
    int*            cnt   = (int*)(ws + 12800000);      //  6,400,000 B
    int*            ovCnt = (int*)(ws + 19200000);      //         64 B
    int2*           ov    = (int2*)(ws + 19200064);     //    262,144 B
    int*            bkt   = (int*)(ws + 19462208);      // 12,800,000 B

    const int E = in_sizes[1] / 2;

    hipMemsetAsync(cnt, 0, 6400064, stream);            // cnt + ovCnt

    mlp_kernel<<<(N_NODES + 255) / 256, 256, 0, stream>>>(
        x, W1, b1, g1, be1, W2, b2, g2, be2, hb);

    int sthreads = (E + 7) / 8;
    scatter_kernel<<<(sthreads + 255) / 256, 256, 0, stream>>>(ei, cnt, bkt, ovCnt, ov, E);

    aggr_kernel<<<(N_NODES + 3) / 4, 256, 0, stream>>>(cnt, bkt, hb, out, ovCnt, ov);
}

// Round 8
// 270.475 us; speedup vs baseline: 1.5290x; 1.0803x over previous
//
#include <hip/hip_runtime.h>

#define N_NODES 100000
#define D_IN 32
#define H 64
#define EPS 1e-5f
#define RSTR 32     // bucket row stride (ints): [cnt, e0..e30] = 128B
#define CAP 31      // entries per row; E[overflow entries] ~ 0.6 (exact ov path)
#define OV_CAP 32768

__device__ __forceinline__ unsigned short f2bf(float f) {
    union { float f; unsigned int u; } c; c.f = f;
    unsigned int b = c.u + 0x7FFFu + ((c.u >> 16) & 1u);   // RNE
    return (unsigned short)(b >> 16);
}
__device__ __forceinline__ float bf2f(unsigned short s) {
    union { unsigned int u; float f; } c; c.u = ((unsigned int)s) << 16;
    return c.f;
}

// ================= fused: scatter (blocks [0,SB)) + MLP (blocks [SB,SB+MB)) =================
// Scatter path: 8 edges/thread; atomic cursor lives IN the bucket row, so the
// returning atomic and the entry write share a cache line (halves random RMW).
// Scatter is grid-limited (2442 waves << resident capacity), so the MLP path's
// register appetite does not cost it parallelism.
// MLP path: R5's proven thread-per-node code, uniform CF -> scalarized weights.
__global__ __launch_bounds__(256, 2) void fused_kernel(
    const float* __restrict__ x,
    const float* __restrict__ W1, const float* __restrict__ b1,
    const float* __restrict__ g1, const float* __restrict__ be1,
    const float* __restrict__ W2, const float* __restrict__ b2,
    const float* __restrict__ g2, const float* __restrict__ be2,
    unsigned short* __restrict__ hb,
    const int* __restrict__ ei, int* __restrict__ bkt,
    int* __restrict__ ovCnt, int2* __restrict__ ov,
    int E, int SB)
{
    if (blockIdx.x < (unsigned)SB) {
        // ---------------- scatter ----------------
        int t = blockIdx.x * 256 + threadIdx.x;
        int e0 = t * 8;
        if (e0 >= E) return;

        int rows[8], cols[8], pos[8];
        if (e0 + 7 < E) {
            int4 r0 = *(const int4*)(ei + e0);
            int4 r1 = *(const int4*)(ei + e0 + 4);
            int4 c0 = *(const int4*)(ei + E + e0);
            int4 c1 = *(const int4*)(ei + E + e0 + 4);
            rows[0]=r0.x; rows[1]=r0.y; rows[2]=r0.z; rows[3]=r0.w;
            rows[4]=r1.x; rows[5]=r1.y; rows[6]=r1.z; rows[7]=r1.w;
            cols[0]=c0.x; cols[1]=c0.y; cols[2]=c0.z; cols[3]=c0.w;
            cols[4]=c1.x; cols[5]=c1.y; cols[6]=c1.z; cols[7]=c1.w;
        } else {
#pragma unroll
            for (int j = 0; j < 8; ++j) {
                int e = e0 + j;
                if (e < E) { rows[j] = ei[e]; cols[j] = ei[E + e]; }
                else rows[j] = -1;
            }
        }
#pragma unroll
        for (int j = 0; j < 8; ++j)
            if (rows[j] >= 0) pos[j] = atomicAdd(&bkt[rows[j] * RSTR], 1);
#pragma unroll
        for (int j = 0; j < 8; ++j) {
            if (rows[j] < 0) continue;
            if (pos[j] < CAP) {
                bkt[rows[j] * RSTR + 1 + pos[j]] = cols[j];   // same line as cursor
            } else {
                int s = atomicAdd(ovCnt, 1);
                if (s < OV_CAP) ov[s] = make_int2(rows[j], cols[j]);
            }
        }
        return;
    }

    // ---------------- MLP: thread-per-node (R5 code, unchanged) ----------------
    int gid = (blockIdx.x - SB) * 256 + threadIdx.x;
    int node = gid < N_NODES ? gid : N_NODES - 1;

    float xr[D_IN];
    {
        const float4* xp = (const float4*)(x + (long long)node * D_IN);
#pragma unroll
        for (int i = 0; i < D_IN / 4; ++i) {
            float4 v = xp[i];
            xr[4*i+0] = v.x; xr[4*i+1] = v.y; xr[4*i+2] = v.z; xr[4*i+3] = v.w;
        }
    }

    float h1[H];
#pragma unroll
    for (int jb = 0; jb < H / 4; ++jb) {
        float4 b = *(const float4*)(b1 + jb * 4);
        h1[4*jb+0] = b.x; h1[4*jb+1] = b.y; h1[4*jb+2] = b.z; h1[4*jb+3] = b.w;
    }
#pragma unroll
    for (int k = 0; k < D_IN; ++k) {
        float xk = xr[k];
#pragma unroll
        for (int jb = 0; jb < H / 4; ++jb) {
            float4 w = *(const float4*)(W1 + k * H + jb * 4);
            h1[4*jb+0] += xk * w.x; h1[4*jb+1] += xk * w.y;
            h1[4*jb+2] += xk * w.z; h1[4*jb+3] += xk * w.w;
        }
    }
    {
        float s0=0,s1=0,s2=0,s3=0, q0=0,q1=0,q2=0,q3=0;
#pragma unroll
        for (int j = 0; j < H; j += 4) {
            s0 += h1[j+0]; s1 += h1[j+1]; s2 += h1[j+2]; s3 += h1[j+3];
            q0 += h1[j+0]*h1[j+0]; q1 += h1[j+1]*h1[j+1];
            q2 += h1[j+2]*h1[j+2]; q3 += h1[j+3]*h1[j+3];
        }
        float mu  = (s0+s1+s2+s3) * (1.0f / H);
        float var = (q0+q1+q2+q3) * (1.0f / H) - mu * mu;
        float rs  = rsqrtf(var + EPS);
#pragma unroll
        for (int jb = 0; jb < H / 4; ++jb) {
            float4 g = *(const float4*)(g1 + jb * 4);
            float4 be = *(const float4*)(be1 + jb * 4);
            h1[4*jb+0] = fmaxf((h1[4*jb+0]-mu)*rs*g.x + be.x, 0.0f);
            h1[4*jb+1] = fmaxf((h1[4*jb+1]-mu)*rs*g.y + be.y, 0.0f);
            h1[4*jb+2] = fmaxf((h1[4*jb+2]-mu)*rs*g.z + be.z, 0.0f);
            h1[4*jb+3] = fmaxf((h1[4*jb+3]-mu)*rs*g.w + be.w, 0.0f);
        }
    }

    float h2[H];
#pragma unroll
    for (int jb = 0; jb < H / 4; ++jb) {
        float4 b = *(const float4*)(b2 + jb * 4);
        h2[4*jb+0] = b.x; h2[4*jb+1] = b.y; h2[4*jb+2] = b.z; h2[4*jb+3] = b.w;
    }
#pragma unroll
    for (int k = 0; k < H; ++k) {
        float hk = h1[k];
#pragma unroll
        for (int jb = 0; jb < H / 4; ++jb) {
            float4 w = *(const float4*)(W2 + k * H + jb * 4);
            h2[4*jb+0] += hk * w.x; h2[4*jb+1] += hk * w.y;
            h2[4*jb+2] += hk * w.z; h2[4*jb+3] += hk * w.w;
        }
    }
    {
        float s0=0,s1=0,s2=0,s3=0, q0=0,q1=0,q2=0,q3=0;
#pragma unroll
        for (int j = 0; j < H; j += 4) {
            s0 += h2[j+0]; s1 += h2[j+1]; s2 += h2[j+2]; s3 += h2[j+3];
            q0 += h2[j+0]*h2[j+0]; q1 += h2[j+1]*h2[j+1];
            q2 += h2[j+2]*h2[j+2]; q3 += h2[j+3]*h2[j+3];
        }
        float mu  = (s0+s1+s2+s3) * (1.0f / H);
        float var = (q0+q1+q2+q3) * (1.0f / H) - mu * mu;
        float rs  = rsqrtf(var + EPS);

        unsigned short* hp = hb + (long long)node * H;
#pragma unroll
        for (int jb = 0; jb < H / 4; ++jb) {
            float4 g = *(const float4*)(g2 + jb * 4);
            float4 be = *(const float4*)(be2 + jb * 4);
            ushort4 u;
            u.x = f2bf(fmaxf((h2[4*jb+0]-mu)*rs*g.x + be.x, 0.0f));
            u.y = f2bf(fmaxf((h2[4*jb+1]-mu)*rs*g.y + be.y, 0.0f));
            u.z = f2bf(fmaxf((h2[4*jb+2]-mu)*rs*g.z + be.z, 0.0f));
            u.w = f2bf(fmaxf((h2[4*jb+3]-mu)*rs*g.w + be.w, 0.0f));
            *(ushort4*)(hp + 4*jb) = u;
        }
    }
}

// ================= pull aggregation: 2 serial memory rounds =================
// Row holds cnt+entries: one unguarded 128B read (8 independent int4) gives
// everything; then all gathers + self-term issue together.
__global__ __launch_bounds__(256) void aggr_kernel(
    const int* __restrict__ bkt,
    const unsigned short* __restrict__ hb, float* __restrict__ out,
    const int* __restrict__ ovCnt, const int2* __restrict__ ov)
{
    int lane = threadIdx.x & 63;
    int node = blockIdx.x * (blockDim.x >> 6) + (threadIdx.x >> 6);
    if (node >= N_NODES) return;

    const int4* b4 = (const int4*)(bkt + node * RSTR);
    int4 q0 = b4[0]; int4 q1 = b4[1]; int4 q2 = b4[2]; int4 q3 = b4[3];
    int4 q4 = b4[4]; int4 q5 = b4[5]; int4 q6 = b4[6]; int4 q7 = b4[7];

    int m = q0.x; if (m > CAP) m = CAP;
    int cols[CAP] = {q0.y,q0.z,q0.w, q1.x,q1.y,q1.z,q1.w, q2.x,q2.y,q2.z,q2.w,
                     q3.x,q3.y,q3.z,q3.w, q4.x,q4.y,q4.z,q4.w, q5.x,q5.y,q5.z,q5.w,
                     q6.x,q6.y,q6.z,q6.w, q7.x,q7.y,q7.z,q7.w};

    // gathers + self-term all independent
    unsigned short v[CAP];
#pragma unroll
    for (int j = 0; j < CAP; ++j)
        if (j < m) v[j] = hb[cols[j] * H + lane];
    float self = bf2f(hb[node * H + lane]);

    float a0 = 0.f, a1 = 0.f, a2 = 0.f, a3 = 0.f;
#pragma unroll
    for (int j = 0; j < CAP; j += 4) {
        if (j + 0 < m) a0 += bf2f(v[j+0]);
        if (j + 1 < m) a1 += bf2f(v[j+1]);
        if (j + 2 < m) a2 += bf2f(v[j+2]);
        if (j + 3 < m) a3 += bf2f(v[j+3]);
    }
    float acc = (a0 + a1) + (a2 + a3);

    // exact overflow drain (normally ~0-2 entries total)
    int nov = *ovCnt; if (nov > OV_CAP) nov = OV_CAP;
    for (int i = 0; i < nov; ++i) {
        int2 rc = ov[i];
        if (rc.x == node) acc += bf2f(hb[rc.y * H + lane]);
    }

    out[node * H + lane] = self + acc;
}

extern "C" void kernel_launch(void* const* d_in, const int* in_sizes, int n_in,
                              void* d_out, int out_size, void* d_ws, size_t ws_size,
                              hipStream_t stream)
{
    const float* x   = (const float*)d_in[0];
    const int*   ei  = (const int*)d_in[1];
    const float* W1  = (const float*)d_in[2];
    const float* b1  = (const float*)d_in[3];
    const float* g1  = (const float*)d_in[4];
    const float* be1 = (const float*)d_in[5];
    const float* W2  = (const float*)d_in[6];
    const float* b2  = (const float*)d_in[7];
    const float* g2  = (const float*)d_in[8];
    const float* be2 = (const float*)d_in[9];

    float* out = (float*)d_out;

    // workspace layout (~25.9 MB)
    char* ws = (char*)d_ws;
    unsigned short* hb    = (unsigned short*)ws;        // 12,800,000 B
    int*            bkt   = (int*)(ws + 12800000);      // 12,800,000 B (100000*32*4)
    int*            ovCnt = (int*)(ws + 25600000);      //         64 B
    int2*           ov    = (int2*)(ws + 25600064);     //    262,144 B

    const int E = in_sizes[1] / 2;

    hipMemsetAsync(bkt, 0, 12800064, stream);           // bkt rows (cnt words) + ovCnt

    const int SB = ((E + 7) / 8 + 255) / 256;           // 611 scatter blocks
    const int MB = (N_NODES + 255) / 256;               // 391 mlp blocks
    fused_kernel<<<SB + MB, 256, 0, stream>>>(
        x, W1, b1, g1, be1, W2, b2, g2, be2, hb,
        ei, bkt, ovCnt, ov, E, SB);

    aggr_kernel<<<(N_NODES + 3) / 4, 256, 0, stream>>>(bkt, hb, out, ovCnt, ov);
}

// Round 9
// 224.330 us; speedup vs baseline: 1.8436x; 1.2057x over previous
//
#include <hip/hip_runtime.h>

#define N_NODES 100000
#define D_IN 32
#define H 64
#define EPS 1e-5f
#define RSTR 32     // bucket row: 32 entry slots (128B), no embedded counter
#define CAP 32
#define OV_CAP 32768

__device__ __forceinline__ unsigned short f2bf(float f) {
    union { float f; unsigned int u; } c; c.f = f;
    unsigned int b = c.u + 0x7FFFu + ((c.u >> 16) & 1u);   // RNE
    return (unsigned short)(b >> 16);
}
__device__ __forceinline__ float bf2f(unsigned short s) {
    union { unsigned int u; float f; } c; c.u = ((unsigned int)s) << 16;
    return c.f;
}

// ================= fused: scatter (blocks [0,SB)) + MLP (blocks [SB,SB+MB)) =================
// Scatter: cursor atomics on a compact 400KB cnt (device-scope RMW at the
// coherent point; small footprint). Bucket entries written NON-TEMPORALLY:
// random 4B stores must not allocate/thrash L2 lines (R8: 80MB writeback).
__global__ __launch_bounds__(256, 2) void fused_kernel(
    const float* __restrict__ x,
    const float* __restrict__ W1, const float* __restrict__ b1,
    const float* __restrict__ g1, const float* __restrict__ be1,
    const float* __restrict__ W2, const float* __restrict__ b2,
    const float* __restrict__ g2, const float* __restrict__ be2,
    unsigned short* __restrict__ hb,
    const int* __restrict__ ei, int* __restrict__ cnt, int* __restrict__ bkt,
    int* __restrict__ ovCnt, int2* __restrict__ ov,
    int E, int SB)
{
    if (blockIdx.x < (unsigned)SB) {
        // ---------------- scatter: 8 edges/thread ----------------
        int t = blockIdx.x * 256 + threadIdx.x;
        int e0 = t * 8;
        if (e0 >= E) return;

        int rows[8], cols[8], pos[8];
        if (e0 + 7 < E) {
            int4 r0 = *(const int4*)(ei + e0);
            int4 r1 = *(const int4*)(ei + e0 + 4);
            int4 c0 = *(const int4*)(ei + E + e0);
            int4 c1 = *(const int4*)(ei + E + e0 + 4);
            rows[0]=r0.x; rows[1]=r0.y; rows[2]=r0.z; rows[3]=r0.w;
            rows[4]=r1.x; rows[5]=r1.y; rows[6]=r1.z; rows[7]=r1.w;
            cols[0]=c0.x; cols[1]=c0.y; cols[2]=c0.z; cols[3]=c0.w;
            cols[4]=c1.x; cols[5]=c1.y; cols[6]=c1.z; cols[7]=c1.w;
        } else {
#pragma unroll
            for (int j = 0; j < 8; ++j) {
                int e = e0 + j;
                if (e < E) { rows[j] = ei[e]; cols[j] = ei[E + e]; }
                else rows[j] = -1;
            }
        }
#pragma unroll
        for (int j = 0; j < 8; ++j)
            if (rows[j] >= 0) pos[j] = atomicAdd(&cnt[rows[j]], 1);
#pragma unroll
        for (int j = 0; j < 8; ++j) {
            if (rows[j] < 0) continue;
            if (pos[j] < CAP) {
                __builtin_nontemporal_store(cols[j], &bkt[rows[j] * RSTR + pos[j]]);
            } else {
                int s = atomicAdd(ovCnt, 1);
                if (s < OV_CAP) ov[s] = make_int2(rows[j], cols[j]);
            }
        }
        return;
    }

    // ---------------- MLP: thread-per-node (unchanged from R8) ----------------
    int gid = (blockIdx.x - SB) * 256 + threadIdx.x;
    int node = gid < N_NODES ? gid : N_NODES - 1;

    float xr[D_IN];
    {
        const float4* xp = (const float4*)(x + (long long)node * D_IN);
#pragma unroll
        for (int i = 0; i < D_IN / 4; ++i) {
            float4 v = xp[i];
            xr[4*i+0] = v.x; xr[4*i+1] = v.y; xr[4*i+2] = v.z; xr[4*i+3] = v.w;
        }
    }

    float h1[H];
#pragma unroll
    for (int jb = 0; jb < H / 4; ++jb) {
        float4 b = *(const float4*)(b1 + jb * 4);
        h1[4*jb+0] = b.x; h1[4*jb+1] = b.y; h1[4*jb+2] = b.z; h1[4*jb+3] = b.w;
    }
#pragma unroll
    for (int k = 0; k < D_IN; ++k) {
        float xk = xr[k];
#pragma unroll
        for (int jb = 0; jb < H / 4; ++jb) {
            float4 w = *(const float4*)(W1 + k * H + jb * 4);
            h1[4*jb+0] += xk * w.x; h1[4*jb+1] += xk * w.y;
            h1[4*jb+2] += xk * w.z; h1[4*jb+3] += xk * w.w;
        }
    }
    {
        float s0=0,s1=0,s2=0,s3=0, q0=0,q1=0,q2=0,q3=0;
#pragma unroll
        for (int j = 0; j < H; j += 4) {
            s0 += h1[j+0]; s1 += h1[j+1]; s2 += h1[j+2]; s3 += h1[j+3];
            q0 += h1[j+0]*h1[j+0]; q1 += h1[j+1]*h1[j+1];
            q2 += h1[j+2]*h1[j+2]; q3 += h1[j+3]*h1[j+3];
        }
        float mu  = (s0+s1+s2+s3) * (1.0f / H);
        float var = (q0+q1+q2+q3) * (1.0f / H) - mu * mu;
        float rs  = rsqrtf(var + EPS);
#pragma unroll
        for (int jb = 0; jb < H / 4; ++jb) {
            float4 g = *(const float4*)(g1 + jb * 4);
            float4 be = *(const float4*)(be1 + jb * 4);
            h1[4*jb+0] = fmaxf((h1[4*jb+0]-mu)*rs*g.x + be.x, 0.0f);
            h1[4*jb+1] = fmaxf((h1[4*jb+1]-mu)*rs*g.y + be.y, 0.0f);
            h1[4*jb+2] = fmaxf((h1[4*jb+2]-mu)*rs*g.z + be.z, 0.0f);
            h1[4*jb+3] = fmaxf((h1[4*jb+3]-mu)*rs*g.w + be.w, 0.0f);
        }
    }

    float h2[H];
#pragma unroll
    for (int jb = 0; jb < H / 4; ++jb) {
        float4 b = *(const float4*)(b2 + jb * 4);
        h2[4*jb+0] = b.x; h2[4*jb+1] = b.y; h2[4*jb+2] = b.z; h2[4*jb+3] = b.w;
    }
#pragma unroll
    for (int k = 0; k < H; ++k) {
        float hk = h1[k];
#pragma unroll
        for (int jb = 0; jb < H / 4; ++jb) {
            float4 w = *(const float4*)(W2 + k * H + jb * 4);
            h2[4*jb+0] += hk * w.x; h2[4*jb+1] += hk * w.y;
            h2[4*jb+2] += hk * w.z; h2[4*jb+3] += hk * w.w;
        }
    }
    {
        float s0=0,s1=0,s2=0,s3=0, q0=0,q1=0,q2=0,q3=0;
#pragma unroll
        for (int j = 0; j < H; j += 4) {
            s0 += h2[j+0]; s1 += h2[j+1]; s2 += h2[j+2]; s3 += h2[j+3];
            q0 += h2[j+0]*h2[j+0]; q1 += h2[j+1]*h2[j+1];
            q2 += h2[j+2]*h2[j+2]; q3 += h2[j+3]*h2[j+3];
        }
        float mu  = (s0+s1+s2+s3) * (1.0f / H);
        float var = (q0+q1+q2+q3) * (1.0f / H) - mu * mu;
        float rs  = rsqrtf(var + EPS);

        unsigned short* hp = hb + (long long)node * H;
#pragma unroll
        for (int jb = 0; jb < H / 4; ++jb) {
            float4 g = *(const float4*)(g2 + jb * 4);
            float4 be = *(const float4*)(be2 + jb * 4);
            ushort4 u;
            u.x = f2bf(fmaxf((h2[4*jb+0]-mu)*rs*g.x + be.x, 0.0f));
            u.y = f2bf(fmaxf((h2[4*jb+1]-mu)*rs*g.y + be.y, 0.0f));
            u.z = f2bf(fmaxf((h2[4*jb+2]-mu)*rs*g.z + be.z, 0.0f));
            u.w = f2bf(fmaxf((h2[4*jb+3]-mu)*rs*g.w + be.w, 0.0f));
            *(ushort4*)(hp + 4*jb) = u;
        }
    }
}

// ================= pull aggregation: 4 nodes per wave =================
// Lane = (sub, c): sub in [0,4) picks the node, c in [0,16) picks a ushort4
// channel quad (8B/lane). One gather instruction = 4 x 128B rows = 512B in
// flight; 16-edge chunks => ~8KB outstanding per wave (4x R8's 2KB).
__global__ __launch_bounds__(256, 2) void aggr_kernel(
    const int* __restrict__ cnt, const int* __restrict__ bkt,
    const unsigned short* __restrict__ hb, float* __restrict__ out,
    const int* __restrict__ ovCnt, const int2* __restrict__ ov)
{
    const int t    = threadIdx.x & 63;
    const int sub  = t >> 4;                       // node-within-wave
    const int c    = t & 15;                       // channel quad
    const int wave = blockIdx.x * 4 + (threadIdx.x >> 6);
    const int node = wave * 4 + sub;               // grid exact: 6250*16 = 100000

    int m = cnt[node];
    if (m > CAP) m = CAP;
    const int base = node * RSTR;

    float a0 = 0.f, a1 = 0.f, a2 = 0.f, a3 = 0.f;
#pragma unroll
    for (int j0 = 0; j0 < CAP; j0 += 16) {
        int cc[16];
#pragma unroll
        for (int i = 0; i < 16; ++i)               // broadcast loads (16 lanes/addr)
            cc[i] = bkt[base + j0 + i];
        uint2 vv[16];
#pragma unroll
        for (int i = 0; i < 16; ++i)               // independent 8B gathers
            if (j0 + i < m)
                vv[i] = *(const uint2*)(hb + ((long long)cc[i] << 6) + (c << 2));
#pragma unroll
        for (int i = 0; i < 16; ++i) {
            if (j0 + i < m) {
                a0 += bf2f((unsigned short)(vv[i].x & 0xFFFFu));
                a1 += bf2f((unsigned short)(vv[i].x >> 16));
                a2 += bf2f((unsigned short)(vv[i].y & 0xFFFFu));
                a3 += bf2f((unsigned short)(vv[i].y >> 16));
            }
        }
    }

    // self term
    {
        uint2 sv = *(const uint2*)(hb + ((long long)node << 6) + (c << 2));
        a0 += bf2f((unsigned short)(sv.x & 0xFFFFu));
        a1 += bf2f((unsigned short)(sv.x >> 16));
        a2 += bf2f((unsigned short)(sv.y & 0xFFFFu));
        a3 += bf2f((unsigned short)(sv.y >> 16));
    }

    // exact overflow drain (normally 0 entries)
    int nov = *ovCnt; if (nov > OV_CAP) nov = OV_CAP;
    for (int i = 0; i < nov; ++i) {
        int2 rc = ov[i];
        if (rc.x == node) {
            uint2 vv = *(const uint2*)(hb + ((long long)rc.y << 6) + (c << 2));
            a0 += bf2f((unsigned short)(vv.x & 0xFFFFu));
            a1 += bf2f((unsigned short)(vv.x >> 16));
            a2 += bf2f((unsigned short)(vv.y & 0xFFFFu));
            a3 += bf2f((unsigned short)(vv.y >> 16));
        }
    }

    *(float4*)(out + ((long long)node << 6) + (c << 2)) = make_float4(a0, a1, a2, a3);
}

extern "C" void kernel_launch(void* const* d_in, const int* in_sizes, int n_in,
                              void* d_out, int out_size, void* d_ws, size_t ws_size,
                              hipStream_t stream)
{
    const float* x   = (const float*)d_in[0];
    const int*   ei  = (const int*)d_in[1];
    const float* W1  = (const float*)d_in[2];
    const float* b1  = (const float*)d_in[3];
    const float* g1  = (const float*)d_in[4];
    const float* be1 = (const float*)d_in[5];
    const float* W2  = (const float*)d_in[6];
    const float* b2  = (const float*)d_in[7];
    const float* g2  = (const float*)d_in[8];
    const float* be2 = (const float*)d_in[9];

    float* out = (float*)d_out;

    // workspace layout (~26.3 MB)
    char* ws = (char*)d_ws;
    unsigned short* hb    = (unsigned short*)ws;        // 12,800,000 B
    int*            cnt   = (int*)(ws + 12800000);      //    400,000 B
    int*            ovCnt = (int*)(ws + 13200000);      //         64 B
    int2*           ov    = (int2*)(ws + 13200064);     //    262,144 B
    int*            bkt   = (int*)(ws + 13462208);      // 12,800,000 B (nt-written, never zeroed)

    const int E = in_sizes[1] / 2;

    hipMemsetAsync(cnt, 0, 400064, stream);             // cnt + ovCnt only (was 12.8MB)

    const int SB = ((E + 7) / 8 + 255) / 256;           // 611 scatter blocks
    const int MB = (N_NODES + 255) / 256;               // 391 mlp blocks
    fused_kernel<<<SB + MB, 256, 0, stream>>>(
        x, W1, b1, g1, be1, W2, b2, g2, be2, hb,
        ei, cnt, bkt, ovCnt, ov, E, SB);

    aggr_kernel<<<N_NODES / 16, 256, 0, stream>>>(cnt, bkt, hb, out, ovCnt, ov);
}

// Round 10
// 209.690 us; speedup vs baseline: 1.9723x; 1.0698x over previous
//
#include <hip/hip_runtime.h>

#define N_NODES 100000
#define D_IN 32
#define H 64
#define EPS 1e-5f
#define RSTR 32     // bucket row: 32 entry slots (128B)
#define CAP 32
#define OV_CAP 32768

typedef float floatx2 __attribute__((ext_vector_type(2)));

__device__ __forceinline__ unsigned short f2bf(float f) {
    union { float f; unsigned int u; } c; c.f = f;
    unsigned int b = c.u + 0x7FFFu + ((c.u >> 16) & 1u);   // RNE
    return (unsigned short)(b >> 16);
}
__device__ __forceinline__ float bf2f(unsigned short s) {
    union { unsigned int u; float f; } c; c.u = ((unsigned int)s) << 16;
    return c.f;
}

// ================= fused: scatter + MLP, Bresenham-interleaved roles =================
// R9 ran scatter blocks [0,611) then MLP [611,1002) -> sequential through the
// block queue (dur ~= sum). Interleaving 3:2 keeps both paths resident on
// every CU throughout -> memory-latency path overlaps VALU path.
__global__ __launch_bounds__(256, 2) void fused_kernel(
    const float* __restrict__ x,
    const float* __restrict__ W1, const float* __restrict__ b1,
    const float* __restrict__ g1, const float* __restrict__ be1,
    const float* __restrict__ W2, const float* __restrict__ b2,
    const float* __restrict__ g2, const float* __restrict__ be2,
    unsigned short* __restrict__ hb, unsigned char* __restrict__ hb8,
    const int* __restrict__ ei, int* __restrict__ cnt, int* __restrict__ bkt,
    int* __restrict__ ovCnt, int2* __restrict__ ov,
    int E, int SB, int TOT)
{
    const int i = blockIdx.x;
    const int before = (int)((long long)i * SB / TOT);
    const int after  = (int)((long long)(i + 1) * SB / TOT);

    if (after > before) {
        // ---------------- scatter: 8 edges/thread ----------------
        int t = before * 256 + threadIdx.x;
        int e0 = t * 8;
        if (e0 >= E) return;

        int rows[8], cols[8], pos[8];
        if (e0 + 7 < E) {
            int4 r0 = *(const int4*)(ei + e0);
            int4 r1 = *(const int4*)(ei + e0 + 4);
            int4 c0 = *(const int4*)(ei + E + e0);
            int4 c1 = *(const int4*)(ei + E + e0 + 4);
            rows[0]=r0.x; rows[1]=r0.y; rows[2]=r0.z; rows[3]=r0.w;
            rows[4]=r1.x; rows[5]=r1.y; rows[6]=r1.z; rows[7]=r1.w;
            cols[0]=c0.x; cols[1]=c0.y; cols[2]=c0.z; cols[3]=c0.w;
            cols[4]=c1.x; cols[5]=c1.y; cols[6]=c1.z; cols[7]=c1.w;
        } else {
#pragma unroll
            for (int j = 0; j < 8; ++j) {
                int e = e0 + j;
                if (e < E) { rows[j] = ei[e]; cols[j] = ei[E + e]; }
                else rows[j] = -1;
            }
        }
#pragma unroll
        for (int j = 0; j < 8; ++j)
            if (rows[j] >= 0) pos[j] = atomicAdd(&cnt[rows[j]], 1);
#pragma unroll
        for (int j = 0; j < 8; ++j) {
            if (rows[j] < 0) continue;
            if (pos[j] < CAP) {
                __builtin_nontemporal_store(cols[j], &bkt[rows[j] * RSTR + pos[j]]);
            } else {
                int s = atomicAdd(ovCnt, 1);
                if (s < OV_CAP) ov[s] = make_int2(rows[j], cols[j]);
            }
        }
        return;
    }

    // ---------------- MLP: thread-per-node ----------------
    int gid = (i - before) * 256 + threadIdx.x;
    int node = gid < N_NODES ? gid : N_NODES - 1;

    float xr[D_IN];
    {
        const float4* xp = (const float4*)(x + (long long)node * D_IN);
#pragma unroll
        for (int i2 = 0; i2 < D_IN / 4; ++i2) {
            float4 v = xp[i2];
            xr[4*i2+0] = v.x; xr[4*i2+1] = v.y; xr[4*i2+2] = v.z; xr[4*i2+3] = v.w;
        }
    }

    float h1[H];
#pragma unroll
    for (int jb = 0; jb < H / 4; ++jb) {
        float4 b = *(const float4*)(b1 + jb * 4);
        h1[4*jb+0] = b.x; h1[4*jb+1] = b.y; h1[4*jb+2] = b.z; h1[4*jb+3] = b.w;
    }
#pragma unroll
    for (int k = 0; k < D_IN; ++k) {
        float xk = xr[k];
#pragma unroll
        for (int jb = 0; jb < H / 4; ++jb) {
            float4 w = *(const float4*)(W1 + k * H + jb * 4);
            h1[4*jb+0] += xk * w.x; h1[4*jb+1] += xk * w.y;
            h1[4*jb+2] += xk * w.z; h1[4*jb+3] += xk * w.w;
        }
    }
    {
        float s0=0,s1=0,s2=0,s3=0, q0=0,q1=0,q2=0,q3=0;
#pragma unroll
        for (int j = 0; j < H; j += 4) {
            s0 += h1[j+0]; s1 += h1[j+1]; s2 += h1[j+2]; s3 += h1[j+3];
            q0 += h1[j+0]*h1[j+0]; q1 += h1[j+1]*h1[j+1];
            q2 += h1[j+2]*h1[j+2]; q3 += h1[j+3]*h1[j+3];
        }
        float mu  = (s0+s1+s2+s3) * (1.0f / H);
        float var = (q0+q1+q2+q3) * (1.0f / H) - mu * mu;
        float rs  = rsqrtf(var + EPS);
#pragma unroll
        for (int jb = 0; jb < H / 4; ++jb) {
            float4 g = *(const float4*)(g1 + jb * 4);
            float4 be = *(const float4*)(be1 + jb * 4);
            h1[4*jb+0] = fmaxf((h1[4*jb+0]-mu)*rs*g.x + be.x, 0.0f);
            h1[4*jb+1] = fmaxf((h1[4*jb+1]-mu)*rs*g.y + be.y, 0.0f);
            h1[4*jb+2] = fmaxf((h1[4*jb+2]-mu)*rs*g.z + be.z, 0.0f);
            h1[4*jb+3] = fmaxf((h1[4*jb+3]-mu)*rs*g.w + be.w, 0.0f);
        }
    }

    float h2[H];
#pragma unroll
    for (int jb = 0; jb < H / 4; ++jb) {
        float4 b = *(const float4*)(b2 + jb * 4);
        h2[4*jb+0] = b.x; h2[4*jb+1] = b.y; h2[4*jb+2] = b.z; h2[4*jb+3] = b.w;
    }
#pragma unroll
    for (int k = 0; k < H; ++k) {
        float hk = h1[k];
#pragma unroll
        for (int jb = 0; jb < H / 4; ++jb) {
            float4 w = *(const float4*)(W2 + k * H + jb * 4);
            h2[4*jb+0] += hk * w.x; h2[4*jb+1] += hk * w.y;
            h2[4*jb+2] += hk * w.z; h2[4*jb+3] += hk * w.w;
        }
    }
    {
        float s0=0,s1=0,s2=0,s3=0, q0=0,q1=0,q2=0,q3=0;
#pragma unroll
        for (int j = 0; j < H; j += 4) {
            s0 += h2[j+0]; s1 += h2[j+1]; s2 += h2[j+2]; s3 += h2[j+3];
            q0 += h2[j+0]*h2[j+0]; q1 += h2[j+1]*h2[j+1];
            q2 += h2[j+2]*h2[j+2]; q3 += h2[j+3]*h2[j+3];
        }
        float mu  = (s0+s1+s2+s3) * (1.0f / H);
        float var = (q0+q1+q2+q3) * (1.0f / H) - mu * mu;
        float rs  = rsqrtf(var + EPS);

        unsigned short* hp = hb + (long long)node * H;
        unsigned int w8[H / 4];
#pragma unroll
        for (int jb = 0; jb < H / 4; ++jb) {
            float4 g = *(const float4*)(g2 + jb * 4);
            float4 be = *(const float4*)(be2 + jb * 4);
            float4 v;
            v.x = fmaxf((h2[4*jb+0]-mu)*rs*g.x + be.x, 0.0f);
            v.y = fmaxf((h2[4*jb+1]-mu)*rs*g.y + be.y, 0.0f);
            v.z = fmaxf((h2[4*jb+2]-mu)*rs*g.z + be.z, 0.0f);
            v.w = fmaxf((h2[4*jb+3]-mu)*rs*g.w + be.w, 0.0f);
            ushort4 u;
            u.x = f2bf(v.x); u.y = f2bf(v.y); u.z = f2bf(v.z); u.w = f2bf(v.w);
            *(ushort4*)(hp + 4*jb) = u;
            int lo = __builtin_amdgcn_cvt_pk_fp8_f32(v.x, v.y, 0, false);
            w8[jb] = (unsigned int)__builtin_amdgcn_cvt_pk_fp8_f32(v.z, v.w, lo, true);
        }
        unsigned int* hp8 = (unsigned int*)(hb8 + (long long)node * H);
#pragma unroll
        for (int q = 0; q < H / 16; ++q)
            *(uint4*)(hp8 + q * 4) = make_uint4(w8[4*q+0], w8[4*q+1], w8[4*q+2], w8[4*q+3]);
    }
}

// ================= pull aggregation: fp8 gathers (64B rows) =================
// aggr is random-line-traffic bound (~1.8 TB/s at 128B bf16 rows, R7 vs R9
// invariant). fp8 rows halve the line traffic: lane = (sub, c), sub picks
// 1 of 4 nodes, c in [0,16) reads a uint (4 fp8 channels); 16 lanes x 4B
// = one full 64B row per node per gather instr.
__global__ __launch_bounds__(256, 2) void aggr_kernel(
    const int* __restrict__ cnt, const int* __restrict__ bkt,
    const unsigned short* __restrict__ hb, const unsigned char* __restrict__ hb8,
    float* __restrict__ out,
    const int* __restrict__ ovCnt, const int2* __restrict__ ov)
{
    const int t    = threadIdx.x & 63;
    const int sub  = t >> 4;                       // node-within-wave
    const int c    = t & 15;                       // channel quad
    const int wave = blockIdx.x * 4 + (threadIdx.x >> 6);
    const int node = wave * 4 + sub;               // grid exact: 6250*16 = 100000

    int m = cnt[node];
    if (m > CAP) m = CAP;
    const int base = node * RSTR;
    const unsigned int* h8 = (const unsigned int*)hb8;  // row stride 16 uints

    float a0 = 0.f, a1 = 0.f, a2 = 0.f, a3 = 0.f;
#pragma unroll
    for (int j0 = 0; j0 < CAP; j0 += 16) {
        int cc[16];
#pragma unroll
        for (int i = 0; i < 16; ++i)               // broadcast loads (16 lanes/addr)
            cc[i] = bkt[base + j0 + i];
        unsigned int vv[16];
#pragma unroll
        for (int i = 0; i < 16; ++i)               // independent 4B gathers (64B/row)
            if (j0 + i < m) vv[i] = h8[(cc[i] << 4) + c];
#pragma unroll
        for (int i = 0; i < 16; ++i) {
            if (j0 + i < m) {
                floatx2 p0 = __builtin_amdgcn_cvt_pk_f32_fp8(vv[i], false);
                floatx2 p1 = __builtin_amdgcn_cvt_pk_f32_fp8(vv[i], true);
                a0 += p0.x; a1 += p0.y; a2 += p1.x; a3 += p1.y;
            }
        }
    }

    // self term (bf16 precision, sequential access)
    {
        uint2 sv = *(const uint2*)(hb + ((long long)node << 6) + (c << 2));
        a0 += bf2f((unsigned short)(sv.x & 0xFFFFu));
        a1 += bf2f((unsigned short)(sv.x >> 16));
        a2 += bf2f((unsigned short)(sv.y & 0xFFFFu));
        a3 += bf2f((unsigned short)(sv.y >> 16));
    }

    // exact overflow drain (normally 0 entries)
    int nov = *ovCnt; if (nov > OV_CAP) nov = OV_CAP;
    for (int i = 0; i < nov; ++i) {
        int2 rc = ov[i];
        if (rc.x == node) {
            uint2 vv = *(const uint2*)(hb + ((long long)rc.y << 6) + (c << 2));
            a0 += bf2f((unsigned short)(vv.x & 0xFFFFu));
            a1 += bf2f((unsigned short)(vv.x >> 16));
            a2 += bf2f((unsigned short)(vv.y & 0xFFFFu));
            a3 += bf2f((unsigned short)(vv.y >> 16));
        }
    }

    *(float4*)(out + ((long long)node << 6) + (c << 2)) = make_float4(a0, a1, a2, a3);
}

extern "C" void kernel_launch(void* const* d_in, const int* in_sizes, int n_in,
                              void* d_out, int out_size, void* d_ws, size_t ws_size,
                              hipStream_t stream)
{
    const float* x   = (const float*)d_in[0];
    const int*   ei  = (const int*)d_in[1];
    const float* W1  = (const float*)d_in[2];
    const float* b1  = (const float*)d_in[3];
    const float* g1  = (const float*)d_in[4];
    const float* be1 = (const float*)d_in[5];
    const float* W2  = (const float*)d_in[6];
    const float* b2  = (const float*)d_in[7];
    const float* g2  = (const float*)d_in[8];
    const float* be2 = (const float*)d_in[9];

    float* out = (float*)d_out;

    // workspace layout (~32.7 MB)
    char* ws = (char*)d_ws;
    unsigned short* hb    = (unsigned short*)ws;        // 12,800,000 B
    unsigned char*  hb8   = (unsigned char*)(ws + 12800000); // 6,400,000 B
    int*            cnt   = (int*)(ws + 19200000);      //    400,000 B
    int*            ovCnt = (int*)(ws + 19600000);      //         64 B
    int2*           ov    = (int2*)(ws + 19600064);     //    262,144 B
    int*            bkt   = (int*)(ws + 19862208);      // 12,800,000 B (nt-written, never zeroed)

    const int E = in_sizes[1] / 2;

    hipMemsetAsync(cnt, 0, 400064, stream);             // cnt + ovCnt

    const int SB = ((E + 7) / 8 + 255) / 256;           // 611 scatter blocks
    const int MB = (N_NODES + 255) / 256;               // 391 mlp blocks
    fused_kernel<<<SB + MB, 256, 0, stream>>>(
        x, W1, b1, g1, be1, W2, b2, g2, be2, hb, hb8,
        ei, cnt, bkt, ovCnt, ov, E, SB, SB + MB);

    aggr_kernel<<<N_NODES / 16, 256, 0, stream>>>(cnt, bkt, hb, hb8, out, ovCnt, ov);
}